// Round 6
// baseline (864.874 us; speedup 1.0000x reference)
//
#include <hip/hip_runtime.h>
#include <hip/hip_fp16.h>

#define N_NODES 10000
#define N_EDGES 30000
#define NODE_DIM 75
#define BOND_DIM 16
#define IN_DIM 64
#define INTERNAL 128
#define FP_DIM 4096
#define N_GRAPHS 16
#define DEPTH 3
#define K_TOT 8256          // 128*64 + 64 (bias block, h==1)

typedef _Float16 half8v __attribute__((ext_vector_type(8)));
typedef float float4v __attribute__((ext_vector_type(4)));

// graph boundaries via binary search on sorted batch
__global__ void k_bounds(const int* __restrict__ batch, int* __restrict__ gstart) {
    int g = threadIdx.x;
    if (g > N_GRAPHS) return;
    int lo = 0, hi = N_NODES;
    while (lo < hi) { int mid = (lo + hi) >> 1; if (batch[mid] < g) lo = mid + 1; else hi = mid; }
    gstart[g] = lo;
}

// msg0 = relu(x @ W_ae + b_ae); writes fp32 + fp16
__global__ void k_atom_expand(const float* __restrict__ x, const float* __restrict__ W,
                              const float* __restrict__ b, float* __restrict__ msg,
                              __half* __restrict__ msg16) {
    int n = blockIdx.x;
    int o = threadIdx.x;          // 64
    __shared__ float xr[NODE_DIM];
    if (o < NODE_DIM) xr[o] = x[(size_t)n * NODE_DIM + o];
    if (o + 64 < NODE_DIM) xr[o + 64] = x[(size_t)n * NODE_DIM + o + 64];
    __syncthreads();
    float acc = b[o];
    #pragma unroll
    for (int k = 0; k < NODE_DIM; ++k) acc = fmaf(xr[k], W[k * IN_DIM + o], acc);
    float v = fmaxf(acc, 0.f);
    msg[(size_t)n * IN_DIM + o] = v;
    msg16[(size_t)n * IN_DIM + o] = __float2half(v);
}

// h = relu(edge_attr @ W_e1 + b_e1) -> fp16  (depth-invariant)
__global__ void k_edge_h16(const float* __restrict__ ea, const float* __restrict__ W1,
                           const float* __restrict__ b1, __half* __restrict__ h) {
    int e = blockIdx.x;
    int j = threadIdx.x;          // 128
    __shared__ float r[BOND_DIM];
    if (j < BOND_DIM) r[j] = ea[(size_t)e * BOND_DIM + j];
    __syncthreads();
    float acc = b1[j];
    #pragma unroll
    for (int k = 0; k < BOND_DIM; ++k) acc = fmaf(r[k], W1[k * INTERNAL + j], acc);
    h[(size_t)e * INTERNAL + j] = __float2half(fmaxf(acc, 0.f));
}

// W2BT[o][K] fp16, K=k*64+i: = W2[k][i*64+o] for k<128; = b2[i*64+o] for K>=8192
// grid.x MUST be exactly K_TOT/64 = 129 (guard added regardless).
__global__ void k_w2bt(const float* __restrict__ W2, const float* __restrict__ b2,
                       __half* __restrict__ W2BT) {
    int K = blockIdx.x * 64 + threadIdx.x;
    int o = blockIdx.y;                       // 0..63
    if (K >= K_TOT) return;
    int k = K >> 6, i = K & 63;
    float v = (k < 128) ? W2[(size_t)k * 4096 + i * 64 + o] : b2[i * 64 + o];
    W2BT[(size_t)o * K_TOT + K] = __float2half(v);
}

// WfpT [4096][64] fp16 from W_fp [64][4096]
__global__ void k_wfpt(const float* __restrict__ Wfp, __half* __restrict__ WfpT) {
    int idx = blockIdx.x * 256 + threadIdx.x;     // 262144
    int k = idx >> 12;
    int n = idx & 4095;
    WfpT[(size_t)n * IN_DIM + k] = __float2half(Wfp[idx]);
}

// per-dst edge counts (depth-invariant)
__global__ void k_counts(const float* __restrict__ ea, const int* __restrict__ dst,
                         float* __restrict__ cntC, float* __restrict__ cntS) {
    int e = blockIdx.x * blockDim.x + threadIdx.x;
    if (e >= N_EDGES) return;
    if (ea[(size_t)e * BOND_DIM + (BOND_DIM - 1)] == 0.f) atomicAdd(&cntC[dst[e]], 1.f);
    else atomicAdd(&cntS[dst[e]], 1.f);
}

// per_edge[e][o] = sum_K A[e][K]*W2BT[o][K], A[e][k*64+i]=h[e][k]*m[src[e]][i],
// bias folded as K-block 8192.. with h==1.
// Partition: block = 128 edges x K-half (grid.y=2); wave = 16 edges, full K-half.
// No reduction: scatter-add is linear, each K-half scatters its partial directly.
__global__ __launch_bounds__(512) void k_edge_mfma2(
    const __half* __restrict__ h16, const __half* __restrict__ msg16,
    const __half* __restrict__ W2BT,
    const int* __restrict__ src, const int* __restrict__ dst,
    const float* __restrict__ ea,
    float* __restrict__ aggC, float* __restrict__ aggS)
{
    __shared__ _Float16 h_lds[128][72];   // row stride 144B: 16B-aligned, 2-way bank alias
    const int tid  = threadIdx.x;
    const int lane = tid & 63;
    const int wid  = tid >> 6;            // 0..7: 16-edge sub-tile
    const int e0   = blockIdx.x * 128;
    const int ky   = blockIdx.y;          // 0/1: K-half
    const int l15  = lane & 15;
    const int lg   = lane >> 4;           // 0..3

    // stage h half-tile [128][64]
    {
        int row = tid >> 2;
        int c0 = (tid & 3) * 16;
        int e = e0 + row; if (e >= N_EDGES) e = N_EDGES - 1;
        const _Float16* hr = (const _Float16*)h16 + (size_t)e * INTERNAL + ky * 64 + c0;
        *(half8v*)&h_lds[row][c0]     = *(const half8v*)hr;
        *(half8v*)&h_lds[row][c0 + 8] = *(const half8v*)(hr + 8);
    }

    // m fragments for this wave's 16 edges (A row = l15)
    int eme = e0 + wid * 16 + l15; if (eme >= N_EDGES) eme = N_EDGES - 1;
    const _Float16* mr = (const _Float16*)msg16 + (size_t)src[eme] * IN_DIM + lg * 8;
    const half8v mfa = *(const half8v*)mr;          // i = lg*8+j
    const half8v mfb = *(const half8v*)(mr + 32);   // i = 32+lg*8+j

    __syncthreads();

    float4v acc[4];
    #pragma unroll
    for (int ob = 0; ob < 4; ++ob) acc[ob] = (float4v){0.f, 0.f, 0.f, 0.f};

    // B pointers: o-row = ob*16+l15, k-offset lg*8, advanced to this K-half
    const _Float16* wb0 = (const _Float16*)W2BT + lg * 8 + (size_t)ky * 4096;
    const _Float16* wb[4];
    #pragma unroll
    for (int ob = 0; ob < 4; ++ob)
        wb[ob] = wb0 + (size_t)(ob * 16 + l15) * K_TOT;

    // main K-half: 128 ksteps = 8 chunks x 16; h chunk preloaded as b128
    const _Float16* hrow = &h_lds[wid * 16 + l15][0];
    for (int kc = 0; kc < 8; ++kc) {
        half8v hreg = *(const half8v*)(hrow + kc * 8);
        #pragma unroll
        for (int t = 0; t < 16; ++t) {            // ksloc = kc*16 + t
            _Float16 hv = hreg[t >> 1];
            half8v A = (t & 1) ? (mfb * hv) : (mfa * hv);
            #pragma unroll
            for (int ob = 0; ob < 4; ++ob) {
                half8v B = *(const half8v*)(wb[ob] + (size_t)kc * 512 + t * 32);
                acc[ob] = __builtin_amdgcn_mfma_f32_16x16x32_f16(A, B, acc[ob], 0, 0, 0);
            }
        }
    }
    // bias kstep: global ks = 256+ky (h == 1); wb already includes +ky*4096
    {
        half8v A = ky ? mfb : mfa;
        const size_t boff = (size_t)(256 + ky) * 32 - (size_t)ky * 4096;
        #pragma unroll
        for (int ob = 0; ob < 4; ++ob) {
            half8v B = *(const half8v*)(wb[ob] + boff);
            acc[ob] = __builtin_amdgcn_mfma_f32_16x16x32_f16(A, B, acc[ob], 0, 0, 0);
        }
    }

    // direct masked scatter of this K-half's partial (linear in per_edge)
    #pragma unroll
    for (int r = 0; r < 4; ++r) {
        int e = e0 + wid * 16 + lg * 4 + r;       // D row = lg*4+r
        if (e < N_EDGES) {
            float* agg = (ea[(size_t)e * BOND_DIM + (BOND_DIM - 1)] == 0.f) ? aggC : aggS;
            float* p = &agg[(size_t)dst[e] * IN_DIM + l15];
            #pragma unroll
            for (int ob = 0; ob < 4; ++ob)
                atomicAdd(p + ob * 16, acc[ob][r]);
        }
    }
}

// msg_new = relu(mean_cov + mean_spa + 2*(msg_old @ W_root + b_conv)); fp32 + fp16
__global__ void k_combine(const float* __restrict__ msg_old, const float* __restrict__ Wr,
                          const float* __restrict__ bc,
                          const float* __restrict__ aggC, const float* __restrict__ aggS,
                          const float* __restrict__ cntC, const float* __restrict__ cntS,
                          float* __restrict__ msg_new, __half* __restrict__ msg16) {
    int n = blockIdx.x, o = threadIdx.x;   // 64
    __shared__ float r[IN_DIM];
    r[o] = msg_old[(size_t)n * IN_DIM + o];
    __syncthreads();
    float root = bc[o];
    #pragma unroll
    for (int k = 0; k < IN_DIM; ++k) root = fmaf(r[k], Wr[k * IN_DIM + o], root);
    float cc = cntC[n], cs = cntS[n];
    float mc = (cc > 0.f) ? aggC[(size_t)n * IN_DIM + o] / cc : 0.f;
    float ms = (cs > 0.f) ? aggS[(size_t)n * IN_DIM + o] / cs : 0.f;
    float v = fmaxf(mc + ms + 2.f * root, 0.f);
    msg_new[(size_t)n * IN_DIM + o] = v;
    msg16[(size_t)n * IN_DIM + o] = __float2half(v);
}

// MFMA fused GEMM + relu + add-pool: out[g,:] += sum_n relu(msg16[n] @ WfpT^T + b_fp)
__global__ __launch_bounds__(256) void k_fp_pool_mfma(
    const __half* __restrict__ msg16, const __half* __restrict__ WfpT,
    const float* __restrict__ bfp, const int* __restrict__ gstart,
    float* __restrict__ out)
{
    const int tid = threadIdx.x, lane = tid & 63, wid = tid >> 6;
    const int g = blockIdx.y;
    const int cbase = blockIdx.x * 256 + wid * 64;
    const int l15 = lane & 15;
    const int kq = (lane >> 4) * 8;
    const int rq = (lane >> 4) * 4;

    const _Float16* wt = (const _Float16*)WfpT;
    const _Float16* mp = (const _Float16*)msg16;

    half8v bf[4][2];
    float bias[4];
    #pragma unroll
    for (int nf = 0; nf < 4; ++nf) {
        int n = cbase + nf * 16 + l15;
        #pragma unroll
        for (int kk = 0; kk < 2; ++kk)
            bf[nf][kk] = *(const half8v*)(wt + (size_t)n * IN_DIM + kk * 32 + kq);
        bias[nf] = bfp[n];
    }

    int n0g = gstart[g], n1g = gstart[g + 1];
    int len = n1g - n0g;
    int chunk = (len + (int)gridDim.z - 1) / (int)gridDim.z;
    int rs = n0g + (int)blockIdx.z * chunk;
    int re = min(rs + chunk, n1g);

    float pool[4] = {0.f, 0.f, 0.f, 0.f};
    for (int r = rs; r < re; r += 16) {
        int node = r + l15;
        if (node >= n1g) node = n1g - 1;
        half8v af0 = *(const half8v*)(mp + (size_t)node * IN_DIM + kq);
        half8v af1 = *(const half8v*)(mp + (size_t)node * IN_DIM + 32 + kq);
        #pragma unroll
        for (int nf = 0; nf < 4; ++nf) {
            float4v d = (float4v){0.f, 0.f, 0.f, 0.f};
            d = __builtin_amdgcn_mfma_f32_16x16x32_f16(af0, bf[nf][0], d, 0, 0, 0);
            d = __builtin_amdgcn_mfma_f32_16x16x32_f16(af1, bf[nf][1], d, 0, 0, 0);
            #pragma unroll
            for (int reg = 0; reg < 4; ++reg) {
                int rr = r + rq + reg;
                if (rr < re) pool[nf] += fmaxf(d[reg] + bias[nf], 0.f);
            }
        }
    }
    #pragma unroll
    for (int nf = 0; nf < 4; ++nf) {
        pool[nf] += __shfl_xor(pool[nf], 16);
        pool[nf] += __shfl_xor(pool[nf], 32);
    }
    if (lane < 16) {
        #pragma unroll
        for (int nf = 0; nf < 4; ++nf)
            atomicAdd(&out[(size_t)g * FP_DIM + cbase + nf * 16 + lane], pool[nf]);
    }
}

extern "C" void kernel_launch(void* const* d_in, const int* in_sizes, int n_in,
                              void* d_out, int out_size, void* d_ws, size_t ws_size,
                              hipStream_t stream) {
    const float* x        = (const float*)d_in[0];
    const int*   eidx     = (const int*)d_in[1];
    const float* ea       = (const float*)d_in[2];
    const int*   batch    = (const int*)d_in[3];
    const float* W_ae     = (const float*)d_in[4];
    const float* b_ae     = (const float*)d_in[5];
    const float* W_e1     = (const float*)d_in[6];
    const float* b_e1     = (const float*)d_in[7];
    const float* W_e2     = (const float*)d_in[8];
    const float* b_e2     = (const float*)d_in[9];
    const float* W_root   = (const float*)d_in[10];
    const float* b_conv   = (const float*)d_in[11];
    const float* W_fp     = (const float*)d_in[12];
    const float* b_fp     = (const float*)d_in[13];
    const int* src = eidx;
    const int* dst = eidx + N_EDGES;
    float* out = (float*)d_out;

    hipMemsetAsync(out, 0, (size_t)out_size * sizeof(float), stream);

    float* ws   = (float*)d_ws;
    float* msgA = ws;
    float* msgB = msgA + 640000;
    float* aggC = msgB + 640000;
    float* aggS = aggC + 640000;
    float* cntC = aggS + 640000;
    float* cntS = cntC + 10000;
    int*   gst  = (int*)(cntS + 10000);                 // 32 ints

    __half* h16   = (__half*)(gst + 32);
    __half* W2BT  = h16 + (size_t)N_EDGES * INTERNAL;   // 3,840,000 halfs
    __half* msg16 = W2BT + (size_t)IN_DIM * K_TOT;      // 528,384 halfs
    __half* WfpT  = msg16 + (size_t)N_NODES * IN_DIM;   // 640,000 halfs

    size_t need = (4ull * 640000 + 2 * 10000 + 32) * 4
                + ((size_t)N_EDGES * INTERNAL + (size_t)IN_DIM * K_TOT
                   + (size_t)N_NODES * IN_DIM + (size_t)FP_DIM * IN_DIM) * 2;
    if (ws_size < need) return;   // fail loudly (out stays 0)

    hipMemsetAsync(cntC, 0, 2 * (size_t)N_NODES * sizeof(float), stream);
    k_bounds<<<1, 32, 0, stream>>>(batch, gst);
    k_atom_expand<<<N_NODES, 64, 0, stream>>>(x, W_ae, b_ae, msgA, msg16);
    k_counts<<<(N_EDGES + 255) / 256, 256, 0, stream>>>(ea, dst, cntC, cntS);
    k_edge_h16<<<N_EDGES, 128, 0, stream>>>(ea, W_e1, b_e1, h16);
    k_w2bt<<<dim3(K_TOT / 64, IN_DIM), 64, 0, stream>>>(W_e2, b_e2, W2BT);  // exactly 129
    k_wfpt<<<(FP_DIM * IN_DIM) / 256, 256, 0, stream>>>(W_fp, WfpT);

    float* cur = msgA;
    float* nxt = msgB;
    for (int d = 0; d < DEPTH; ++d) {
        hipMemsetAsync(aggC, 0, 2 * (size_t)N_NODES * IN_DIM * sizeof(float), stream);
        k_edge_mfma2<<<dim3((N_EDGES + 127) / 128, 2), 512, 0, stream>>>(
            h16, msg16, W2BT, src, dst, ea, aggC, aggS);
        k_combine<<<N_NODES, 64, 0, stream>>>(cur, W_root, b_conv, aggC, aggS,
                                              cntC, cntS, nxt, msg16);
        k_fp_pool_mfma<<<dim3(FP_DIM / 256, N_GRAPHS, 4), 256, 0, stream>>>(
            msg16, WfpT, b_fp, gst, out);
        float* t = cur; cur = nxt; nxt = t;
    }
}

// Round 7
// 574.798 us; speedup vs baseline: 1.5047x; 1.5047x over previous
//
#include <hip/hip_runtime.h>
#include <hip/hip_fp16.h>

#define N_NODES 10000
#define N_EDGES 30000
#define NODE_DIM 75
#define BOND_DIM 16
#define IN_DIM 64
#define INTERNAL 128
#define FP_DIM 4096
#define N_GRAPHS 16
#define DEPTH 3

typedef _Float16 half8v __attribute__((ext_vector_type(8)));
typedef float float4v __attribute__((ext_vector_type(4)));

// graph boundaries via binary search on sorted batch
__global__ void k_bounds(const int* __restrict__ batch, int* __restrict__ gstart) {
    int g = threadIdx.x;
    if (g > N_GRAPHS) return;
    int lo = 0, hi = N_NODES;
    while (lo < hi) { int mid = (lo + hi) >> 1; if (batch[mid] < g) lo = mid + 1; else hi = mid; }
    gstart[g] = lo;
}

// msg0 = relu(x @ W_ae + b_ae); writes fp32 + fp16
__global__ void k_atom_expand(const float* __restrict__ x, const float* __restrict__ W,
                              const float* __restrict__ b, float* __restrict__ msg,
                              __half* __restrict__ msg16) {
    int n = blockIdx.x;
    int o = threadIdx.x;          // 64
    __shared__ float xr[NODE_DIM];
    if (o < NODE_DIM) xr[o] = x[(size_t)n * NODE_DIM + o];
    if (o + 64 < NODE_DIM) xr[o + 64] = x[(size_t)n * NODE_DIM + o + 64];
    __syncthreads();
    float acc = b[o];
    #pragma unroll
    for (int k = 0; k < NODE_DIM; ++k) acc = fmaf(xr[k], W[k * IN_DIM + o], acc);
    float v = fmaxf(acc, 0.f);
    msg[(size_t)n * IN_DIM + o] = v;
    msg16[(size_t)n * IN_DIM + o] = __float2half(v);
}

// h = relu(edge_attr @ W_e1 + b_e1) -> fp16  (depth-invariant)
__global__ void k_edge_h16(const float* __restrict__ ea, const float* __restrict__ W1,
                           const float* __restrict__ b1, __half* __restrict__ h) {
    int e = blockIdx.x;
    int j = threadIdx.x;          // 128
    __shared__ float r[BOND_DIM];
    if (j < BOND_DIM) r[j] = ea[(size_t)e * BOND_DIM + j];
    __syncthreads();
    float acc = b1[j];
    #pragma unroll
    for (int k = 0; k < BOND_DIM; ++k) acc = fmaf(r[k], W1[k * INTERNAL + j], acc);
    h[(size_t)e * INTERNAL + j] = __float2half(fmaxf(acc, 0.f));
}

// transpose-convert W2 [128][4096] fp32 -> W2T [4096][128] fp16
__global__ void k_w2t(const float* __restrict__ W2, __half* __restrict__ W2T) {
    int idx = blockIdx.x * 256 + threadIdx.x;     // 524288 total
    int k = idx >> 12;
    int n = idx & 4095;
    W2T[(size_t)n * INTERNAL + k] = __float2half(W2[idx]);
}

// WfpT [4096][64] fp16 from W_fp [64][4096]
__global__ void k_wfpt(const float* __restrict__ Wfp, __half* __restrict__ WfpT) {
    int idx = blockIdx.x * 256 + threadIdx.x;     // 262144
    int k = idx >> 12;
    int n = idx & 4095;
    WfpT[(size_t)n * IN_DIM + k] = __float2half(Wfp[idx]);
}

// per-dst edge counts (depth-invariant)
__global__ void k_counts(const float* __restrict__ ea, const int* __restrict__ dst,
                         float* __restrict__ cntC, float* __restrict__ cntS) {
    int e = blockIdx.x * blockDim.x + threadIdx.x;
    if (e >= N_EDGES) return;
    if (ea[(size_t)e * BOND_DIM + (BOND_DIM - 1)] == 0.f) atomicAdd(&cntC[dst[e]], 1.f);
    else atomicAdd(&cntS[dst[e]], 1.f);
}

// One-time MFMA GEMM: w[E,4096] = h16[E,128] @ W2 + b2, fp16 row-major output.
// D layout (verified R2/R3): row = edge, col = n. Epilogue stages D through LDS
// so global stores are 16B/lane, 256B-contiguous per edge row (full 128B lines).
// Grid: x = n-block (32 of 128), y = edge-block (235 of 128). Block = 4 waves,
// each wave = 32 edges x 128 n.
__global__ __launch_bounds__(256) void k_wgemm(
    const __half* __restrict__ h16, const __half* __restrict__ W2T,
    const float* __restrict__ b2, __half* __restrict__ w)
{
    __shared__ _Float16 st[4][32][136];   // per-wave stage; 272B row stride
    const int tid  = threadIdx.x;
    const int lane = tid & 63;
    const int wv   = tid >> 6;
    const int nbase = blockIdx.x * 128;
    const int ebase = blockIdx.y * 128 + wv * 32;
    const int l15 = lane & 15;
    const int kq  = (lane >> 4) * 8;

    const _Float16* hp = (const _Float16*)h16;
    const _Float16* wp = (const _Float16*)W2T;

    // A frags (rows = edges): [mi][kk]
    half8v a[2][4];
    #pragma unroll
    for (int mi = 0; mi < 2; ++mi) {
        int e = ebase + mi * 16 + l15;
        if (e >= N_EDGES) e = N_EDGES - 1;
        const _Float16* arow = hp + (size_t)e * INTERNAL;
        #pragma unroll
        for (int kk = 0; kk < 4; ++kk)
            a[mi][kk] = *(const half8v*)(arow + kk * 32 + kq);
    }

    float4v acc[2][8];
    #pragma unroll
    for (int mi = 0; mi < 2; ++mi)
        #pragma unroll
        for (int ni = 0; ni < 8; ++ni)
            acc[mi][ni] = (float4v){0.f, 0.f, 0.f, 0.f};

    #pragma unroll
    for (int kk = 0; kk < 4; ++kk) {
        half8v bw[8];                     // B frags (cols = n): 8 independent loads
        #pragma unroll
        for (int ni = 0; ni < 8; ++ni) {
            int n = nbase + ni * 16 + l15;
            bw[ni] = *(const half8v*)(wp + (size_t)n * INTERNAL + kk * 32 + kq);
        }
        #pragma unroll
        for (int ni = 0; ni < 8; ++ni) {
            acc[0][ni] = __builtin_amdgcn_mfma_f32_16x16x32_f16(a[0][kk], bw[ni], acc[0][ni], 0, 0, 0);
            acc[1][ni] = __builtin_amdgcn_mfma_f32_16x16x32_f16(a[1][kk], bw[ni], acc[1][ni], 0, 0, 0);
        }
    }

    // stage to LDS with bias (D: col n = l15-frag, row = (lane>>4)*4 + r)
    const int rq = (lane >> 4) * 4;
    #pragma unroll
    for (int ni = 0; ni < 8; ++ni) {
        float bias = b2[nbase + ni * 16 + l15];
        #pragma unroll
        for (int mi = 0; mi < 2; ++mi)
            #pragma unroll
            for (int r = 0; r < 4; ++r)
                st[wv][mi * 16 + rq + r][ni * 16 + l15] = (_Float16)(acc[mi][ni][r] + bias);
    }
    __syncthreads();

    // read back coalesced, store 16B/lane (4 edge rows per instruction)
    #pragma unroll
    for (int it = 0; it < 8; ++it) {
        int erow = it * 4 + (lane >> 4);
        half8v v = *(const half8v*)&st[wv][erow][l15 * 8];
        int e = ebase + erow;
        if (e < N_EDGES)
            *(half8v*)((_Float16*)w + (size_t)e * FP_DIM + nbase + l15 * 8) = v;
    }
}

// Per depth: per_edge[e] = m[src[e]] @ w[e] (64x64 fp16), fused masked scatter-add.
// One wave per edge; 8 batched 16B loads/lane (contiguous 1KB/instr), then shfl/fma.
__global__ __launch_bounds__(256) void k_edge_apply(
    const float* __restrict__ msg, const __half* __restrict__ w,
    const int* __restrict__ src, const int* __restrict__ dst,
    const float* __restrict__ ea,
    float* __restrict__ aggC, float* __restrict__ aggS)
{
    const int lane = threadIdx.x & 63;
    const int e = blockIdx.x * 4 + (threadIdx.x >> 6);
    if (e >= N_EDGES) return;
    const float mv = msg[(size_t)src[e] * IN_DIM + lane];
    const half8v* wrow = (const half8v*)((const _Float16*)w + (size_t)e * FP_DIM);
    const int ig = lane >> 3;
    const int oc = lane & 7;

    half8v w8[8];
    #pragma unroll
    for (int t = 0; t < 8; ++t)
        w8[t] = wrow[(ig + 8 * t) * 8 + oc];

    float acc[8] = {0.f, 0.f, 0.f, 0.f, 0.f, 0.f, 0.f, 0.f};
    #pragma unroll
    for (int t = 0; t < 8; ++t) {
        float mi = __shfl(mv, ig + 8 * t);
        #pragma unroll
        for (int j = 0; j < 8; ++j) acc[j] = fmaf(mi, (float)w8[t][j], acc[j]);
    }
    #pragma unroll
    for (int d = 8; d < 64; d <<= 1)
        #pragma unroll
        for (int j = 0; j < 8; ++j) acc[j] += __shfl_xor(acc[j], d);
    if (ig == 0) {
        float* agg = (ea[(size_t)e * BOND_DIM + (BOND_DIM - 1)] == 0.f) ? aggC : aggS;
        float* p = &agg[(size_t)dst[e] * IN_DIM + oc * 8];
        #pragma unroll
        for (int j = 0; j < 8; ++j) atomicAdd(p + j, acc[j]);
    }
}

// msg_new = relu(mean_cov + mean_spa + 2*(msg_old @ W_root + b_conv)); fp32 + fp16
__global__ void k_combine(const float* __restrict__ msg_old, const float* __restrict__ Wr,
                          const float* __restrict__ bc,
                          const float* __restrict__ aggC, const float* __restrict__ aggS,
                          const float* __restrict__ cntC, const float* __restrict__ cntS,
                          float* __restrict__ msg_new, __half* __restrict__ msg16) {
    int n = blockIdx.x, o = threadIdx.x;   // 64
    __shared__ float r[IN_DIM];
    r[o] = msg_old[(size_t)n * IN_DIM + o];
    __syncthreads();
    float root = bc[o];
    #pragma unroll
    for (int k = 0; k < IN_DIM; ++k) root = fmaf(r[k], Wr[k * IN_DIM + o], root);
    float cc = cntC[n], cs = cntS[n];
    float mc = (cc > 0.f) ? aggC[(size_t)n * IN_DIM + o] / cc : 0.f;
    float ms = (cs > 0.f) ? aggS[(size_t)n * IN_DIM + o] / cs : 0.f;
    float v = fmaxf(mc + ms + 2.f * root, 0.f);
    msg_new[(size_t)n * IN_DIM + o] = v;
    msg16[(size_t)n * IN_DIM + o] = __float2half(v);
}

// MFMA fused GEMM + relu + add-pool: out[g,:] += sum_n relu(msg16[n] @ WfpT^T + b_fp)
// Software-pipelined A loads.
__global__ __launch_bounds__(256) void k_fp_pool_mfma(
    const __half* __restrict__ msg16, const __half* __restrict__ WfpT,
    const float* __restrict__ bfp, const int* __restrict__ gstart,
    float* __restrict__ out)
{
    const int tid = threadIdx.x, lane = tid & 63, wid = tid >> 6;
    const int g = blockIdx.y;
    const int cbase = blockIdx.x * 256 + wid * 64;
    const int l15 = lane & 15;
    const int kq = (lane >> 4) * 8;
    const int rq = (lane >> 4) * 4;

    const _Float16* wt = (const _Float16*)WfpT;
    const _Float16* mp = (const _Float16*)msg16;

    half8v bf[4][2];
    float bias[4];
    #pragma unroll
    for (int nf = 0; nf < 4; ++nf) {
        int n = cbase + nf * 16 + l15;
        #pragma unroll
        for (int kk = 0; kk < 2; ++kk)
            bf[nf][kk] = *(const half8v*)(wt + (size_t)n * IN_DIM + kk * 32 + kq);
        bias[nf] = bfp[n];
    }

    int n0g = gstart[g], n1g = gstart[g + 1];
    int len = n1g - n0g;
    int chunk = (len + (int)gridDim.z - 1) / (int)gridDim.z;
    int rs = n0g + (int)blockIdx.z * chunk;
    int re = min(rs + chunk, n1g);
    if (rs >= re) return;

    float pool[4] = {0.f, 0.f, 0.f, 0.f};
    int node0 = rs + l15; if (node0 >= n1g) node0 = n1g - 1;
    half8v af0 = *(const half8v*)(mp + (size_t)node0 * IN_DIM + kq);
    half8v af1 = *(const half8v*)(mp + (size_t)node0 * IN_DIM + 32 + kq);
    for (int r = rs; r < re; r += 16) {
        // prefetch next row-tile
        half8v nf0 = af0, nf1 = af1;
        if (r + 16 < re) {
            int node = r + 16 + l15; if (node >= n1g) node = n1g - 1;
            nf0 = *(const half8v*)(mp + (size_t)node * IN_DIM + kq);
            nf1 = *(const half8v*)(mp + (size_t)node * IN_DIM + 32 + kq);
        }
        #pragma unroll
        for (int nf = 0; nf < 4; ++nf) {
            float4v d = (float4v){0.f, 0.f, 0.f, 0.f};
            d = __builtin_amdgcn_mfma_f32_16x16x32_f16(af0, bf[nf][0], d, 0, 0, 0);
            d = __builtin_amdgcn_mfma_f32_16x16x32_f16(af1, bf[nf][1], d, 0, 0, 0);
            #pragma unroll
            for (int reg = 0; reg < 4; ++reg) {
                int rr = r + rq + reg;
                if (rr < re) pool[nf] += fmaxf(d[reg] + bias[nf], 0.f);
            }
        }
        af0 = nf0; af1 = nf1;
    }
    #pragma unroll
    for (int nf = 0; nf < 4; ++nf) {
        pool[nf] += __shfl_xor(pool[nf], 16);
        pool[nf] += __shfl_xor(pool[nf], 32);
    }
    if (lane < 16) {
        #pragma unroll
        for (int nf = 0; nf < 4; ++nf)
            atomicAdd(&out[(size_t)g * FP_DIM + cbase + nf * 16 + lane], pool[nf]);
    }
}

extern "C" void kernel_launch(void* const* d_in, const int* in_sizes, int n_in,
                              void* d_out, int out_size, void* d_ws, size_t ws_size,
                              hipStream_t stream) {
    const float* x        = (const float*)d_in[0];
    const int*   eidx     = (const int*)d_in[1];
    const float* ea       = (const float*)d_in[2];
    const int*   batch    = (const int*)d_in[3];
    const float* W_ae     = (const float*)d_in[4];
    const float* b_ae     = (const float*)d_in[5];
    const float* W_e1     = (const float*)d_in[6];
    const float* b_e1     = (const float*)d_in[7];
    const float* W_e2     = (const float*)d_in[8];
    const float* b_e2     = (const float*)d_in[9];
    const float* W_root   = (const float*)d_in[10];
    const float* b_conv   = (const float*)d_in[11];
    const float* W_fp     = (const float*)d_in[12];
    const float* b_fp     = (const float*)d_in[13];
    const int* src = eidx;
    const int* dst = eidx + N_EDGES;
    float* out = (float*)d_out;

    hipMemsetAsync(out, 0, (size_t)out_size * sizeof(float), stream);

    float* ws   = (float*)d_ws;
    float* msgA = ws;
    float* msgB = msgA + 640000;
    float* aggC = msgB + 640000;
    float* aggS = aggC + 640000;
    float* cntC = aggS + 640000;
    float* cntS = cntC + 10000;
    int*   gst  = (int*)(cntS + 10000);                 // 32 ints

    __half* h16   = (__half*)(gst + 32);
    __half* W2T   = h16 + (size_t)N_EDGES * INTERNAL;   // 3,840,000 halfs
    __half* wbig  = W2T + (size_t)FP_DIM * INTERNAL;    // 524,288 halfs
    __half* msg16 = wbig + (size_t)N_EDGES * FP_DIM;    // 122,880,000 halfs
    __half* WfpT  = msg16 + (size_t)N_NODES * IN_DIM;   // 640,000 halfs

    size_t need = (4ull * 640000 + 2 * 10000 + 32) * 4
                + ((size_t)N_EDGES * INTERNAL + (size_t)FP_DIM * INTERNAL
                   + (size_t)N_EDGES * FP_DIM + (size_t)N_NODES * IN_DIM
                   + (size_t)FP_DIM * IN_DIM) * 2;
    if (ws_size < need) return;   // fail loudly (out stays 0)

    hipMemsetAsync(cntC, 0, 2 * (size_t)N_NODES * sizeof(float), stream);
    k_bounds<<<1, 32, 0, stream>>>(batch, gst);
    k_atom_expand<<<N_NODES, 64, 0, stream>>>(x, W_ae, b_ae, msgA, msg16);
    k_counts<<<(N_EDGES + 255) / 256, 256, 0, stream>>>(ea, dst, cntC, cntS);
    k_edge_h16<<<N_EDGES, 128, 0, stream>>>(ea, W_e1, b_e1, h16);
    k_w2t<<<(FP_DIM * INTERNAL) / 256, 256, 0, stream>>>(W_e2, W2T);
    k_wfpt<<<(FP_DIM * IN_DIM) / 256, 256, 0, stream>>>(W_fp, WfpT);
    k_wgemm<<<dim3(FP_DIM / 128, (N_EDGES + 127) / 128), 256, 0, stream>>>(
        h16, W2T, b_e2, wbig);

    float* cur = msgA;
    float* nxt = msgB;
    for (int d = 0; d < DEPTH; ++d) {
        hipMemsetAsync(aggC, 0, 2 * (size_t)N_NODES * IN_DIM * sizeof(float), stream);
        k_edge_apply<<<(N_EDGES + 3) / 4, 256, 0, stream>>>(
            cur, wbig, src, dst, ea, aggC, aggS);
        k_combine<<<N_NODES, 64, 0, stream>>>(cur, W_root, b_conv, aggC, aggS,
                                              cntC, cntS, nxt, msg16);
        k_fp_pool_mfma<<<dim3(FP_DIM / 256, N_GRAPHS, 8), 256, 0, stream>>>(
            msg16, WfpT, b_fp, gst, out);
        float* t = cur; cur = nxt; nxt = t;
    }
}